// Round 12
// baseline (424.871 us; speedup 1.0000x reference)
//
#include <hip/hip_runtime.h>

typedef _Float16 f16;
typedef _Float16 f16x8 __attribute__((ext_vector_type(8)));
typedef __bf16 bf16x8 __attribute__((ext_vector_type(8)));
typedef __bf16 bf16x4 __attribute__((ext_vector_type(4)));
typedef float floatx4 __attribute__((ext_vector_type(4)));
typedef unsigned short u16;
typedef unsigned int u32;

#define B_N   8
#define T_SEQ 4096
#define DIM   64
#define QT    64    // q rows per block; 8 waves split keys
#define KT    256   // keys per iter (32 per wave x 8 waves)
#define NIT   (T_SEQ / KT)          // 16
#define PSTR  40    // P row stride in u16 (80 B; rows 16B-aligned)
#define OSTR  68    // epilogue O row stride in f32
#define XSTR  72    // prep LDS row stride in u16
#define LOG2E 1.44269504f
// fragment = 512 u16 (1 KB): lane (qd*16+ln) holds rows[ln], k-chunk qd*8..+8
#define FRAG  512
#define KTILE_FRAGS 32   // KT/16 row-blocks * 2 ks

#if __has_builtin(__builtin_amdgcn_exp2f)
#define EXP2(x) __builtin_amdgcn_exp2f(x)
#else
#define EXP2(x) exp2f(x)
#endif

// ---- prep: fragment-major Kswz/Qswz (f16, Q pre-scaled by log2e), Vswz (bf16 V^T) ----
__launch_bounds__(256, 2)
__global__ void prep_kernel(const float* __restrict__ X, const float* __restrict__ W,
                            u16* __restrict__ Kswz, u16* __restrict__ Qswz,
                            u16* __restrict__ Vswz) {
  __shared__ __attribute__((aligned(16))) u16 Xs[DIM * XSTR];  // f16 X tile [t][d]
  __shared__ __attribute__((aligned(16))) u16 Wt[DIM * XSTR];  // f16 W^T [e][d]
  __shared__ __attribute__((aligned(16))) u16 Qs[DIM * XSTR];  // f16 Q tile [t][e]
  const int tid = threadIdx.x;
  const int lane = tid & 63, w = tid >> 6, qd = lane >> 4, ln = lane & 15;
  const int b = blockIdx.y;
  const int t0 = blockIdx.x * 64;
  const long xbase = ((long)b * T_SEQ + t0) * DIM;

  // stage X (f16) and W^T (f16) into LDS
  {
    const int r = tid >> 2, c0 = (tid & 3) * 16;
    float v[16];
#pragma unroll
    for (int i = 0; i < 4; i++)
      *(float4*)&v[i * 4] = *(const float4*)(X + xbase + (long)r * DIM + c0 + i * 4);
    u16 h[16];
#pragma unroll
    for (int j = 0; j < 16; j++) h[j] = __builtin_bit_cast(u16, (f16)v[j]);
    *(uint4*)&Xs[r * XSTR + c0] = *(uint4*)&h[0];
    *(uint4*)&Xs[r * XSTR + c0 + 8] = *(uint4*)&h[8];
    float wv[16];
#pragma unroll
    for (int i = 0; i < 4; i++)
      *(float4*)&wv[i * 4] = *(const float4*)(W + r * DIM + c0 + i * 4);
#pragma unroll
    for (int j = 0; j < 16; j++) Wt[(c0 + j) * XSTR + r] = __builtin_bit_cast(u16, (f16)wv[j]);
  }
  __syncthreads();

  // K fragments: wave w -> row-block blockIdx.x*4 + w; coalesced 1KB stores
  {
    const long R = (long)b * (T_SEQ / 16) + blockIdx.x * 4 + w;
#pragma unroll
    for (int ks = 0; ks < 2; ks++) {
      f16x8 kv = *(const f16x8*)&Xs[(w * 16 + ln) * XSTR + ks * 32 + qd * 8];
      *(f16x8*)(Kswz + (R * 2 + ks) * FRAG + lane * 8) = kv;
    }
  }

  // Q = X@W via MFMA (wave w owns rows w*16..+16), scaled by log2e, to Qs (wave-local)
  {
    const int wq = w * 16;
    floatx4 acc[4];
#pragma unroll
    for (int ct = 0; ct < 4; ct++) acc[ct] = (floatx4)0.0f;
#pragma unroll
    for (int ks = 0; ks < 2; ks++) {
      f16x8 aX = *(const f16x8*)&Xs[(wq + ln) * XSTR + ks * 32 + qd * 8];
#pragma unroll
      for (int ct = 0; ct < 4; ct++) {
        f16x8 bW = *(const f16x8*)&Wt[(ct * 16 + ln) * XSTR + ks * 32 + qd * 8];
        acc[ct] = __builtin_amdgcn_mfma_f32_16x16x32_f16(aX, bW, acc[ct], 0, 0, 0);
      }
    }
#pragma unroll
    for (int ct = 0; ct < 4; ct++)
#pragma unroll
      for (int r = 0; r < 4; r++)
        Qs[(wq + qd * 4 + r) * XSTR + ct * 16 + ln] =
            __builtin_bit_cast(u16, (f16)(acc[ct][r] * LOG2E));
  }

  // V fragments: wave w -> d-block Cb = b*4+w; V^T[d][t] = X[t][d] as bf16
  {
    const long Cb = (long)b * 4 + w;
    const int J0 = blockIdx.x * 2;
#pragma unroll
    for (int J = 0; J < 2; J++) {
      bf16x8 vv;
#pragma unroll
      for (int j = 0; j < 8; j++) {
        f16 hv = __builtin_bit_cast(f16, Xs[(J * 32 + qd * 8 + j) * XSTR + w * 16 + ln]);
        vv[j] = (__bf16)(float)hv;
      }
      *(bf16x8*)(Vswz + (Cb * (T_SEQ / 32) + J0 + J) * FRAG + lane * 8) = vv;
    }
  }

  // Q fragments from Qs: wave-local rows (w*16+ln) — no barrier needed
  {
    const long R = (long)b * (T_SEQ / 16) + blockIdx.x * 4 + w;
#pragma unroll
    for (int ks = 0; ks < 2; ks++) {
      f16x8 qv = *(const f16x8*)&Qs[(w * 16 + ln) * XSTR + ks * 32 + qd * 8];
      *(f16x8*)(Qswz + (R * 2 + ks) * FRAG + lane * 8) = qv;
    }
  }
}

// One pipelined step; consumes kbuf and refills it with tile ktCur+2.
// ALL register-array indices compile-time.
__device__ __forceinline__ void attn_step(
    const u16* __restrict__ pKf, const u16* __restrict__ pVf, u16* __restrict__ Pw,
    f16x8 (&kbuf)[2][2], const f16x8 (&aQ)[4][2],
    floatx4 (&O)[4][4], float (&lacc)[4], int ktCur, int ln, int qd) {
  // this tile's V (issued early; consumed after QK+softmax)
  const long voff = (long)ktCur * (8 * FRAG);
  bf16x8 bV[4];
#pragma unroll
  for (int cd = 0; cd < 4; cd++)
    bV[cd] = *(const bf16x8*)(pVf + voff + (long)cd * ((T_SEQ / 32) * FRAG));

  // S^T = K Q^T : D[k = ct*16+qd*4+r][q = rb*16+ln]
  floatx4 St[2][4];
#pragma unroll
  for (int ct = 0; ct < 2; ct++)
#pragma unroll
    for (int rb = 0; rb < 4; rb++) St[ct][rb] = (floatx4)0.0f;
#pragma unroll
  for (int ks = 0; ks < 2; ks++)
#pragma unroll
    for (int ct = 0; ct < 2; ct++)
#pragma unroll
      for (int rb = 0; rb < 4; rb++)
        St[ct][rb] = __builtin_amdgcn_mfma_f32_16x16x32_f16(kbuf[ct][ks], aQ[rb][ks], St[ct][rb], 0, 0, 0);

  // refill kbuf with tile ktCur+2 (prefetch distance = one unrolled iteration)
  const long koffn = (long)((ktCur + 2) & (NIT - 1)) * (KTILE_FRAGS * FRAG);
#pragma unroll
  for (int ct = 0; ct < 2; ct++)
#pragma unroll
    for (int ks = 0; ks < 2; ks++)
      kbuf[ct][ks] = *(const f16x8*)(pKf + koffn + (ct * 2 + ks) * FRAG);

  // P = 2^S'; per-lane l (q = ln); k-contiguous b64 P-writes
#pragma unroll
  for (int rb = 0; rb < 4; rb++)
#pragma unroll
    for (int ct = 0; ct < 2; ct++) {
      bf16x4 pk;
      float ps = 0.f;
#pragma unroll
      for (int r = 0; r < 4; r++) {
        float p = EXP2(St[ct][rb][r]);
        ps += p;
        pk[r] = (__bf16)p;
      }
      lacc[rb] += ps;
      *(uint2*)&Pw[(rb * 16 + ln) * PSTR + ct * 16 + qd * 4] = __builtin_bit_cast(uint2, pk);
    }

  // O += P V
#pragma unroll
  for (int rb = 0; rb < 4; rb++) {
    bf16x8 aP = *(const bf16x8*)&Pw[(rb * 16 + ln) * PSTR + qd * 8];
#pragma unroll
    for (int cd = 0; cd < 4; cd++)
      O[rb][cd] = __builtin_amdgcn_mfma_f32_16x16x32_bf16(aP, bV[cd], O[rb][cd], 0, 0, 0);
  }
}

// ---- main: 8-wave blocks; swizzled operands; K reg double-buffer ----
__launch_bounds__(512, 4)
__global__ void attn_kernel(const u16* __restrict__ Kswz, const u16* __restrict__ Qswz,
                            const u16* __restrict__ Vswz, float* __restrict__ out) {
  __shared__ __attribute__((aligned(16))) u16 Ps[8 * QT * PSTR];  // 40960 B; Opart aliases
  __shared__ float lpart[8][QT];                                   // 2048 B

  float* Opart = (float*)Ps;  // 8*16*OSTR*4 = 34816 B <= 40960

  const int tid = threadIdx.x;
  const int lane = tid & 63;
  const int w = tid >> 6;          // 0..7
  const int qd = lane >> 4;
  const int ln = lane & 15;
  const int bid = blockIdx.x;
  const int b = bid & 7;           // batch == XCD for L2 affinity
  const int q0 = (bid >> 3) * QT;
  const long bbase = (long)b * T_SEQ * DIM;

  // wave w owns keys [kt*256 + w*32, +32): key row-blocks kt*16 + w*2 + ct
  const u16* pKf = Kswz + ((long)b * (T_SEQ / 16) + w * 2) * 2 * FRAG + lane * 8;
  const u16* pVf = Vswz + ((long)b * 4) * (T_SEQ / 32) * FRAG + (long)w * FRAG + lane * 8;
  u16* Pw = &Ps[w * (QT * PSTR)];

  // Q A-fragments pinned (64 rows x 64 d), coalesced loads
  f16x8 aQ[4][2];
#pragma unroll
  for (int rb = 0; rb < 4; rb++)
#pragma unroll
    for (int ks = 0; ks < 2; ks++)
      aQ[rb][ks] = *(const f16x8*)(Qswz +
          (((long)b * (T_SEQ / 16) + (q0 >> 4) + rb) * 2 + ks) * FRAG + lane * 8);

  floatx4 O[4][4];
  float lacc[4] = {0.f, 0.f, 0.f, 0.f};
#pragma unroll
  for (int rb = 0; rb < 4; rb++)
#pragma unroll
    for (int cd = 0; cd < 4; cd++) O[rb][cd] = (floatx4)0.0f;

  // K buffers: bKa holds tile 0, bKb holds tile 1
  f16x8 bKa[2][2], bKb[2][2];
#pragma unroll
  for (int ct = 0; ct < 2; ct++)
#pragma unroll
    for (int ks = 0; ks < 2; ks++) {
      bKa[ct][ks] = *(const f16x8*)(pKf + (ct * 2 + ks) * FRAG);
      bKb[ct][ks] = *(const f16x8*)(pKf + KTILE_FRAGS * FRAG + (ct * 2 + ks) * FRAG);
    }

#pragma unroll 1
  for (int kt = 0; kt < NIT; kt += 2) {
    attn_step(pKf, pVf, Pw, bKa, aQ, O, lacc, kt, ln, qd);
    attn_step(pKf, pVf, Pw, bKb, aQ, O, lacc, kt + 1, ln, qd);
  }

  // l: per-lane (q = ln) partials; reduce across qd lanes
#pragma unroll
  for (int rb = 0; rb < 4; rb++) {
    float v = lacc[rb];
    v += __shfl_xor(v, 16, 64);
    v += __shfl_xor(v, 32, 64);
    if (qd == 0) lpart[w][rb * 16 + ln] = v;
  }

  // epilogue: cross-wave O reduction over 8 waves, 4 rounds of 16 rows
  const int erow = tid >> 5;        // 0..15
  const int ec = (tid & 31) * 2;    // 0..62, float2 per thread
#pragma unroll 1
  for (int rb = 0; rb < 4; rb++) {
    __syncthreads();  // round 0: all waves done with Ps + lpart published
#pragma unroll
    for (int cd = 0; cd < 4; cd++)
#pragma unroll
      for (int r = 0; r < 4; r++)
        Opart[w * 16 * OSTR + (qd * 4 + r) * OSTR + cd * 16 + ln] = O[rb][cd][r];
    __syncthreads();
    float sx = 0.f, sy = 0.f, l = 0.f;
#pragma unroll
    for (int ww = 0; ww < 8; ww++) {
      float2 s = *(const float2*)&Opart[ww * 16 * OSTR + erow * OSTR + ec];
      sx += s.x; sy += s.y;
      l += lpart[ww][rb * 16 + erow];
    }
    float inv = 1.0f / l;
    float2 o; o.x = sx * inv; o.y = sy * inv;
    *(float2*)(out + bbase + (long)(q0 + rb * 16 + erow) * DIM + ec) = o;
  }
}

extern "C" void kernel_launch(void* const* d_in, const int* in_sizes, int n_in,
                              void* d_out, int out_size, void* d_ws, size_t ws_size,
                              hipStream_t stream) {
  const float* X = (const float*)d_in[0];
  const float* W = (const float*)d_in[1];
  float* out = (float*)d_out;
  const size_t SZ = (size_t)B_N * T_SEQ * DIM * 2;  // 4 MB per u16 array
  u16* Kswz = (u16*)d_ws;
  u16* Qswz = (u16*)((char*)d_ws + SZ);
  u16* Vswz = (u16*)((char*)d_ws + 2 * SZ);
  prep_kernel<<<dim3(T_SEQ / 64, B_N), 256, 0, stream>>>(X, W, Kswz, Qswz, Vswz);
  attn_kernel<<<dim3(B_N * (T_SEQ / QT)), 512, 0, stream>>>(Kswz, Qswz, Vswz, out);
}

// Round 13
// 105.676 us; speedup vs baseline: 4.0205x; 4.0205x over previous
//
#include <hip/hip_runtime.h>

typedef _Float16 f16;
typedef _Float16 f16x8 __attribute__((ext_vector_type(8)));
typedef __bf16 bf16x8 __attribute__((ext_vector_type(8)));
typedef __bf16 bf16x4 __attribute__((ext_vector_type(4)));
typedef float floatx4 __attribute__((ext_vector_type(4)));
typedef unsigned short u16;
typedef unsigned int u32;

#define B_N   8
#define T_SEQ 4096
#define DIM   64
#define QT    64     // q rows per block
#define KT    256    // keys per iter (32 per wave x 8 waves)
#define NIT   (T_SEQ / KT)          // 16
#define PSTR2 264    // P row stride in u16 (528 B = 33*16: aligned, even bank spread)
#define XSTR  72     // prep LDS row stride in u16
#define LOG2E 1.44269504f
#define FRAG  512    // fragment = 512 u16 (1 KB): lane holds row[ln], k-chunk qd*8..+8

#if __has_builtin(__builtin_amdgcn_exp2f)
#define EXP2(x) __builtin_amdgcn_exp2f(x)
#else
#define EXP2(x) exp2f(x)
#endif

// ---- prep: fragment-major Kswz/Qswz (f16, Q pre-scaled by log2e), Vswz (bf16 V^T) ----
__launch_bounds__(256, 2)
__global__ void prep_kernel(const float* __restrict__ X, const float* __restrict__ W,
                            u16* __restrict__ Kswz, u16* __restrict__ Qswz,
                            u16* __restrict__ Vswz) {
  __shared__ __attribute__((aligned(16))) u16 Xs[DIM * XSTR];  // f16 X tile [t][d]
  __shared__ __attribute__((aligned(16))) u16 Wt[DIM * XSTR];  // f16 W^T [e][d]
  __shared__ __attribute__((aligned(16))) u16 Qs[DIM * XSTR];  // f16 Q tile [t][e]
  const int tid = threadIdx.x;
  const int lane = tid & 63, w = tid >> 6, qd = lane >> 4, ln = lane & 15;
  const int b = blockIdx.y;
  const int t0 = blockIdx.x * 64;
  const long xbase = ((long)b * T_SEQ + t0) * DIM;

  {
    const int r = tid >> 2, c0 = (tid & 3) * 16;
    float v[16];
#pragma unroll
    for (int i = 0; i < 4; i++)
      *(float4*)&v[i * 4] = *(const float4*)(X + xbase + (long)r * DIM + c0 + i * 4);
    u16 h[16];
#pragma unroll
    for (int j = 0; j < 16; j++) h[j] = __builtin_bit_cast(u16, (f16)v[j]);
    *(uint4*)&Xs[r * XSTR + c0] = *(uint4*)&h[0];
    *(uint4*)&Xs[r * XSTR + c0 + 8] = *(uint4*)&h[8];
    float wv[16];
#pragma unroll
    for (int i = 0; i < 4; i++)
      *(float4*)&wv[i * 4] = *(const float4*)(W + r * DIM + c0 + i * 4);
#pragma unroll
    for (int j = 0; j < 16; j++) Wt[(c0 + j) * XSTR + r] = __builtin_bit_cast(u16, (f16)wv[j]);
  }
  __syncthreads();

  // K fragments: coalesced 1KB stores
  {
    const long R = (long)b * (T_SEQ / 16) + blockIdx.x * 4 + w;
#pragma unroll
    for (int ks = 0; ks < 2; ks++) {
      f16x8 kv = *(const f16x8*)&Xs[(w * 16 + ln) * XSTR + ks * 32 + qd * 8];
      *(f16x8*)(Kswz + (R * 2 + ks) * FRAG + lane * 8) = kv;
    }
  }

  // Q = X@W via MFMA, scaled by log2e, to Qs (wave-local rows)
  {
    const int wq = w * 16;
    floatx4 acc[4];
#pragma unroll
    for (int ct = 0; ct < 4; ct++) acc[ct] = (floatx4)0.0f;
#pragma unroll
    for (int ks = 0; ks < 2; ks++) {
      f16x8 aX = *(const f16x8*)&Xs[(wq + ln) * XSTR + ks * 32 + qd * 8];
#pragma unroll
      for (int ct = 0; ct < 4; ct++) {
        f16x8 bW = *(const f16x8*)&Wt[(ct * 16 + ln) * XSTR + ks * 32 + qd * 8];
        acc[ct] = __builtin_amdgcn_mfma_f32_16x16x32_f16(aX, bW, acc[ct], 0, 0, 0);
      }
    }
#pragma unroll
    for (int ct = 0; ct < 4; ct++)
#pragma unroll
      for (int r = 0; r < 4; r++)
        Qs[(wq + qd * 4 + r) * XSTR + ct * 16 + ln] =
            __builtin_bit_cast(u16, (f16)(acc[ct][r] * LOG2E));
  }

  // V fragments: wave w -> d-block Cb = b*4+w
  {
    const long Cb = (long)b * 4 + w;
    const int J0 = blockIdx.x * 2;
#pragma unroll
    for (int J = 0; J < 2; J++) {
      bf16x8 vv;
#pragma unroll
      for (int j = 0; j < 8; j++) {
        f16 hv = __builtin_bit_cast(f16, Xs[(J * 32 + qd * 8 + j) * XSTR + w * 16 + ln]);
        vv[j] = (__bf16)(float)hv;
      }
      *(bf16x8*)(Vswz + (Cb * (T_SEQ / 32) + J0 + J) * FRAG + lane * 8) = vv;
    }
  }

  // Q fragments from Qs (wave-local rows — no barrier needed)
  {
    const long R = (long)b * (T_SEQ / 16) + blockIdx.x * 4 + w;
#pragma unroll
    for (int ks = 0; ks < 2; ks++) {
      f16x8 qv = *(const f16x8*)&Qs[(w * 16 + ln) * XSTR + ks * 32 + qd * 8];
      *(f16x8*)(Qswz + (R * 2 + ks) * FRAG + lane * 8) = qv;
    }
  }
}

// ---- main: 8-wave blocks; phase A (QK+exp, k-split) / phase B (PV, d x k split) ----
__launch_bounds__(512, 4)
__global__ void attn_kernel(const u16* __restrict__ Kswz, const u16* __restrict__ Qswz,
                            const u16* __restrict__ Vswz, float* __restrict__ out) {
  __shared__ __attribute__((aligned(16))) u16 Ps[QT * PSTR2];  // 33792 B; Opart aliases
  __shared__ float lpart[8][QT];                                // 2048 B

  float* Opart = (float*)Ps;  // 2 kh x 32 q x 68 f32 = 17408 B <= 33792

  const int tid = threadIdx.x;
  const int lane = tid & 63;
  const int w = tid >> 6;           // 0..7
  const int qd = lane >> 4;
  const int ln = lane & 15;
  const int dq = w & 3;             // phase-B d-quarter
  const int kh = w >> 2;            // phase-B key-half
  const int bid = blockIdx.x;
  const int b = bid & 7;            // batch == XCD for L2 affinity
  const int q0 = (bid >> 3) * QT;
  const long bbase = (long)b * T_SEQ * DIM;

  const u16* pKf = Kswz + ((long)b * (T_SEQ / 16) + w * 2) * 2 * FRAG + lane * 8;
  const u16* pVf = Vswz + ((long)(b * 4 + dq)) * (T_SEQ / 32) * FRAG + lane * 8;

  // Q A-fragments pinned (64 rows x 64 d)
  f16x8 aQ[4][2];
#pragma unroll
  for (int rb = 0; rb < 4; rb++)
#pragma unroll
    for (int ks = 0; ks < 2; ks++)
      aQ[rb][ks] = *(const f16x8*)(Qswz +
          (((long)b * (T_SEQ / 16) + (q0 >> 4) + rb) * 2 + ks) * FRAG + lane * 8);

  floatx4 O[4];                      // O[q 64][d 16]: 4 row-blocks x 1 d-block
  float lacc[4] = {0.f, 0.f, 0.f, 0.f};
#pragma unroll
  for (int rb = 0; rb < 4; rb++) O[rb] = (floatx4)0.0f;

#pragma unroll 1
  for (int kt = 0; kt < NIT; kt++) {
    // ---- phase A: this wave's 32 keys -> S^T, exp, P to shared LDS ----
    f16x8 bK[2][2];
#pragma unroll
    for (int ct = 0; ct < 2; ct++)
#pragma unroll
      for (int ks = 0; ks < 2; ks++)
        bK[ct][ks] = *(const f16x8*)(pKf + ((long)(kt * 16 + ct) * 2 + ks) * FRAG);

    floatx4 St[2][4];
#pragma unroll
    for (int ct = 0; ct < 2; ct++)
#pragma unroll
      for (int rb = 0; rb < 4; rb++) St[ct][rb] = (floatx4)0.0f;
#pragma unroll
    for (int ks = 0; ks < 2; ks++)
#pragma unroll
      for (int ct = 0; ct < 2; ct++)
#pragma unroll
        for (int rb = 0; rb < 4; rb++)
          St[ct][rb] = __builtin_amdgcn_mfma_f32_16x16x32_f16(bK[ct][ks], aQ[rb][ks], St[ct][rb], 0, 0, 0);

    // P = 2^S' (Q pre-scaled); per-lane l (q = ln); b64 writes into shared P
#pragma unroll
    for (int rb = 0; rb < 4; rb++)
#pragma unroll
      for (int ct = 0; ct < 2; ct++) {
        bf16x4 pk;
        float ps = 0.f;
#pragma unroll
        for (int r = 0; r < 4; r++) {
          float p = EXP2(St[ct][rb][r]);
          ps += p;
          pk[r] = (__bf16)p;
        }
        lacc[rb] += ps;
        *(uint2*)&Ps[(rb * 16 + ln) * PSTR2 + w * 32 + ct * 16 + qd * 4] =
            __builtin_bit_cast(uint2, pk);
      }

    // V loads issued before the barrier (independent of P)
    bf16x8 bV[4];
#pragma unroll
    for (int ks = 0; ks < 4; ks++)
      bV[ks] = *(const bf16x8*)(pVf + (long)(kt * 8 + kh * 4 + ks) * FRAG);

    __syncthreads();  // all P(kt) visible

    // ---- phase B: O[64q][16d at dq] += P[:, kh*128..+128] V ----
#pragma unroll
    for (int rb = 0; rb < 4; rb++)
#pragma unroll
      for (int ks = 0; ks < 4; ks++) {
        bf16x8 aP = *(const bf16x8*)&Ps[(rb * 16 + ln) * PSTR2 + kh * 128 + ks * 32 + qd * 8];
        O[rb] = __builtin_amdgcn_mfma_f32_16x16x32_bf16(aP, bV[ks], O[rb], 0, 0, 0);
      }

    __syncthreads();  // all P(kt) reads done before next iter's writes
  }

  // l partials: reduce across qd lanes; lpart[w][q]
#pragma unroll
  for (int rb = 0; rb < 4; rb++) {
    float v = lacc[rb];
    v += __shfl_xor(v, 16, 64);
    v += __shfl_xor(v, 32, 64);
    if (qd == 0) lpart[w][rb * 16 + ln] = v;
  }

  // epilogue: 2 rounds of 32 q-rows; Opart[kh][32q][68] aliases Ps
#pragma unroll 1
  for (int g = 0; g < 2; g++) {
    __syncthreads();  // round 0: last P reads + lpart published; round 1: prior reads done
#pragma unroll
    for (int h = 0; h < 2; h++) {
      const int rb = g * 2 + h;
#pragma unroll
      for (int r = 0; r < 4; r++)
        Opart[(kh * 32 + h * 16 + qd * 4 + r) * 68 + dq * 16 + ln] = O[rb][r];
    }
    __syncthreads();
    const int ql = tid >> 4;          // 0..31
    const int d0 = (tid & 15) * 4;    // 0..60
    const int q = g * 32 + ql;
    float4 s0 = *(const float4*)&Opart[(0 * 32 + ql) * 68 + d0];
    float4 s1 = *(const float4*)&Opart[(1 * 32 + ql) * 68 + d0];
    float l = 0.f;
#pragma unroll
    for (int ww = 0; ww < 8; ww++) l += lpart[ww][q];
    float inv = 1.0f / l;
    float4 o;
    o.x = (s0.x + s1.x) * inv;
    o.y = (s0.y + s1.y) * inv;
    o.z = (s0.z + s1.z) * inv;
    o.w = (s0.w + s1.w) * inv;
    *(float4*)(out + bbase + (long)(q0 + q) * DIM + d0) = o;
  }
}

extern "C" void kernel_launch(void* const* d_in, const int* in_sizes, int n_in,
                              void* d_out, int out_size, void* d_ws, size_t ws_size,
                              hipStream_t stream) {
  const float* X = (const float*)d_in[0];
  const float* W = (const float*)d_in[1];
  float* out = (float*)d_out;
  const size_t SZ = (size_t)B_N * T_SEQ * DIM * 2;  // 4 MB per u16 array
  u16* Kswz = (u16*)d_ws;
  u16* Qswz = (u16*)((char*)d_ws + SZ);
  u16* Vswz = (u16*)((char*)d_ws + 2 * SZ);
  prep_kernel<<<dim3(T_SEQ / 64, B_N), 256, 0, stream>>>(X, W, Kswz, Qswz, Vswz);
  attn_kernel<<<dim3(B_N * (T_SEQ / QT)), 512, 0, stream>>>(Kswz, Qswz, Vswz, out);
}